// Round 17
// baseline (130.125 us; speedup 1.0000x reference)
//
#include <hip/hip_runtime.h>
#include <stdint.h>

#pragma clang fp contract(off)

#define NB 16
#define NC 80
#define P_TOT 17064
#define P4 (P_TOT / 4)
#define PRE_K 1000
#define POST_K 100

__device__ __forceinline__ float sigmoidf_(float x) {
  return 1.0f / (1.0f + expf(-x));
}

// Decode (monotonicity trick: argmax over classes == argmax over raw logits;
// exact score computed once for the winner). 20 class loads batched into
// registers; after the quad-reduce each lane decodes its OWN location.
__global__ __launch_bounds__(256, 2) void decode_kernel(
    const float* __restrict__ cls0, const float* __restrict__ reg0, const float* __restrict__ ctr0,
    const float* __restrict__ cls1, const float* __restrict__ reg1, const float* __restrict__ ctr1,
    const float* __restrict__ cls2, const float* __restrict__ reg2, const float* __restrict__ ctr2,
    const float* __restrict__ cls3, const float* __restrict__ reg3, const float* __restrict__ ctr3,
    const float* __restrict__ cls4, const float* __restrict__ reg4, const float* __restrict__ ctr4,
    int* __restrict__ labels, float* __restrict__ boxes,
    unsigned long long* __restrict__ keys)
{
  int quad = blockIdx.x * 64 + (threadIdx.x >> 2);
  int t4 = threadIdx.x & 3;
  int n = blockIdx.y;
  if (quad >= P4) return;
  int p0 = quad * 4;
  int off, wsh, hw; float stride; const float *cls, *reg, *ctr;
  if (p0 < 12800)      { off = 0;     wsh = 7; hw = 12800; stride = 8.f;   cls = cls0; reg = reg0; ctr = ctr0; }
  else if (p0 < 16000) { off = 12800; wsh = 6; hw = 3200;  stride = 16.f;  cls = cls1; reg = reg1; ctr = ctr1; }
  else if (p0 < 16800) { off = 16000; wsh = 5; hw = 800;   stride = 32.f;  cls = cls2; reg = reg2; ctr = ctr2; }
  else if (p0 < 17008) { off = 16800; wsh = 4; hw = 208;   stride = 64.f;  cls = cls3; reg = reg3; ctr = ctr3; }
  else                 { off = 17008; wsh = 3; hw = 56;    stride = 128.f; cls = cls4; reg = reg4; ctr = ctr4; }
  int loc0 = p0 - off;
  int y = loc0 >> wsh;
  int x0 = loc0 & ((1 << wsh) - 1);
  float py = (float)y * stride + 0.5f * stride;

  int c0 = t4 * 20;
  const float* cptr = cls + (size_t)n * NC * hw + (size_t)c0 * hw + loc0;
  float4 cv[20];
  #pragma unroll
  for (int k = 0; k < 20; ++k)
    cv[k] = *reinterpret_cast<const float4*>(cptr + (size_t)k * hw);

  float best[4] = { -3.4e38f, -3.4e38f, -3.4e38f, -3.4e38f };
  int bl[4] = { c0, c0, c0, c0 };
  #pragma unroll
  for (int k = 0; k < 20; ++k) {
    int c = c0 + k;
    if (cv[k].x > best[0]) { best[0] = cv[k].x; bl[0] = c; }
    if (cv[k].y > best[1]) { best[1] = cv[k].y; bl[1] = c; }
    if (cv[k].z > best[2]) { best[2] = cv[k].z; bl[2] = c; }
    if (cv[k].w > best[3]) { best[3] = cv[k].w; bl[3] = c; }
  }
  #pragma unroll
  for (int e = 0; e < 4; ++e) {
    #pragma unroll
    for (int d = 1; d <= 2; d <<= 1) {
      float ob = __shfl_xor(best[e], d);
      int ol = __shfl_xor(bl[e], d);
      if (ob > best[e] || (ob == best[e] && ol < bl[e])) { best[e] = ob; bl[e] = ol; }
    }
  }

  int e = t4;
  int loce = loc0 + e;
  float sctr_e = sigmoidf_(ctr[(size_t)n * hw + loce]);
  const float* rbase = reg + (size_t)n * 4 * hw + loce;
  float dl = rbase[0];
  float dt = rbase[(size_t)hw];
  float dr = rbase[(size_t)2 * hw];
  float db = rbase[(size_t)3 * hw];

  float s = sqrtf(sigmoidf_(best[e]) * sctr_e);
  float val = (s > 0.05f) ? s : 0.0f;
  float px = (float)(x0 + e) * stride + 0.5f * stride;
  float x1 = fminf(fmaxf(px - dl, 0.f), 1024.f);
  float y1 = fminf(fmaxf(py - dt, 0.f), 800.f);
  float x2 = fminf(fmaxf(px + dr, 0.f), 1024.f);
  float y2 = fminf(fmaxf(py + db, 0.f), 800.f);

  size_t o = (size_t)n * P_TOT + p0 + e;
  labels[o] = bl[e];
  *reinterpret_cast<float4*>(boxes + 4 * o) = make_float4(x1, y1, x2, y2);
  keys[o] = ((unsigned long long)__float_as_uint(val) << 32)
          | (unsigned long long)(0xFFFFFFFFu - (unsigned)(p0 + e));
}

// Fused tail: top-k (sort-free) + gather-to-LDS + in-block suppression
// triangle + ballot-fixpoint greedy + finalize. One block per batch.
// LDS layout: smem0[80KB] = hist(64KB)+skey(16KB), overlaid by T (69.6KB)
// AFTER the gather barrier. tb/sc/lb/tbo/areas are separate static arrays.
__global__ __launch_bounds__(1024) void tail_kernel(
    const unsigned long long* __restrict__ keys,
    const float* __restrict__ boxes, const int* __restrict__ labels,
    float* __restrict__ out)
{
  int n = blockIdx.x;
  int tid = threadIdx.x;
  int wave = tid >> 6;
  int lane = tid & 63;

  __shared__ __align__(16) char smem0[16384 * 4 + 2048 * 8];  // 80 KB
  unsigned* hist = (unsigned*)smem0;
  unsigned long long* skey = (unsigned long long*)(smem0 + 16384 * 4);
  unsigned long long* T = (unsigned long long*)smem0;  // overlay post-gather
  __shared__ float4 tbo[1024];
  __shared__ float areas[1024];
  __shared__ float4 tb[1024];
  __shared__ float sc[1024];
  __shared__ int lb[1024];
  __shared__ unsigned Wt[16], Wsuf[16];
  __shared__ unsigned s_d, s_M;
  __shared__ unsigned long long keptw[16];
  __shared__ unsigned sk[1024], sz[1024];

  for (int i = tid; i < 16384; i += 1024) hist[i] = 0;
  tbo[tid] = make_float4(0.f, 0.f, 0.f, 0.f);
  areas[tid] = 0.f;
  tb[tid] = make_float4(0.f, 0.f, 0.f, 0.f);
  sc[tid] = 0.f;
  lb[tid] = 0;
  __syncthreads();

  const unsigned long long* bk = keys + (size_t)n * P_TOT;
  for (int p = tid; p < P_TOT; p += 1024) {
    unsigned h = (unsigned)(bk[p] >> 48);   // scores in [0,1] -> h < 16384
    atomicAdd(&hist[h], 1u);
  }
  __syncthreads();

  // strip sums (16 bins/thread) + two-level shfl suffix scan
  unsigned bvs[16];
  unsigned ssum = 0;
  #pragma unroll
  for (int q = 0; q < 16; ++q) { bvs[q] = hist[tid * 16 + q]; ssum += bvs[q]; }
  unsigned v = ssum;
  #pragma unroll
  for (int d = 1; d < 64; d <<= 1) {
    unsigned t = __shfl_down(v, d);
    if (lane + d < 64) v += t;
  }
  if (lane == 0) Wt[wave] = v;
  __syncthreads();
  if (wave == 0 && lane < 16) {
    unsigned wv = Wt[lane];
    unsigned own = wv;
    #pragma unroll
    for (int d = 1; d < 16; d <<= 1) {
      unsigned t = __shfl_down(wv, d);
      if (lane + d < 16) wv += t;
    }
    Wsuf[lane] = wv - own;
  }
  __syncthreads();
  unsigned At = v + Wsuf[wave];
  unsigned An = At - ssum;
  if (At >= PRE_K && An < PRE_K) {   // unique crossing strip (monotone)
    unsigned cum = An;
    int d = tid * 16;
    unsigned M = 0;
    bool done = false;
    #pragma unroll
    for (int b = 15; b >= 0; --b) {
      if (!done) {
        cum += bvs[b];
        if (cum >= PRE_K) { d = tid * 16 + b; M = cum; done = true; }
      }
    }
    s_d = (unsigned)d;
    s_M = M;
  }
  __syncthreads();
  unsigned dsel = s_d;
  {
    unsigned cum = An;
    #pragma unroll
    for (int b = 15; b >= 0; --b) {
      unsigned h = (unsigned)(tid * 16 + b);
      if (h >= dsel) hist[h] = cum << 16;
      cum += bvs[b];
    }
  }
  __syncthreads();
  // scatter candidates (slot = base + arrival, guard < 2048)
  for (int p = tid; p < P_TOT; p += 1024) {
    unsigned long long k = bk[p];
    unsigned h = (unsigned)(k >> 48);
    if (h >= dsel) {
      unsigned old = atomicAdd(&hist[h], 1u);
      unsigned slot = (old >> 16) + (old & 0xFFFFu);
      if (slot < 2048) skey[slot] = k;
    }
  }
  __syncthreads();
  // rank within bin segment + gather into LDS (boxes/scores/labels + offset)
  unsigned Mcap = s_M < 2048u ? s_M : 2048u;
  #pragma unroll
  for (int e = 0; e < 2; ++e) {
    unsigned sidx = (unsigned)tid + e * 1024;
    if (sidx < Mcap) {
      unsigned long long k = skey[sidx];
      unsigned h = (unsigned)(k >> 48);
      unsigned info = hist[h];
      unsigned start = info >> 16;
      unsigned end = start + (info & 0xFFFFu);
      if (end > 2048u) end = 2048u;
      unsigned rank = 0;
      for (unsigned q = start; q < end; ++q)
        rank += (skey[q] > k) ? 1u : 0u;
      unsigned pos = start + rank;
      if (pos < PRE_K) {
        unsigned idx = 0xFFFFFFFFu - (unsigned)(k & 0xFFFFFFFFu);
        float scv = __uint_as_float((unsigned)(k >> 32));
        size_t src = (size_t)n * P_TOT + idx;
        float4 b4 = *reinterpret_cast<const float4*>(boxes + 4 * src);
        int L = labels[src];
        float offv = (float)L * 4096.0f;
        float4 bo = make_float4(b4.x + offv, b4.y + offv, b4.z + offv, b4.w + offv);
        tb[pos] = b4;
        sc[pos] = scv;
        lb[pos] = L;
        tbo[pos] = bo;
        areas[pos] = (bo.z - bo.x) * (bo.w - bo.y);
      }
    }
  }
  __syncthreads();   // hist/skey dead; T overlay begins

  // suppression triangle: pair p -> (w,c), c<=w; wave handles pairs p=wave+16q.
  // Lane l computes word for column j=w*64+l vs rows c*64+b (b=0..63).
  for (int p = wave; p < 136; p += 16) {
    int w = 0;
    while ((w + 1) * (w + 2) / 2 <= p) ++w;
    int c = p - w * (w + 1) / 2;
    int j = w * 64 + lane;
    float4 bj = tbo[j];
    float aj = areas[j];
    unsigned long long m = 0, mb = 0;
    int ibase = c * 64;
    #pragma unroll
    for (int b = 0; b < 64; ++b) {
      float4 bi = tbo[ibase + b];
      float ai = areas[ibase + b];
      float lx = fmaxf(bi.x, bj.x), ly = fmaxf(bi.y, bj.y);
      float rx = fminf(bi.z, bj.z), ry = fminf(bi.w, bj.w);
      float iw = fmaxf(rx - lx, 0.f), ih = fmaxf(ry - ly, 0.f);
      float inter = iw * ih;
      float denom = ai + aj - inter + 1e-9f;
      float t = inter - 0.6f * denom;
      if (t > 0.f) m |= (1ull << b);
      if (fabsf(t) <= denom * 7.62939453125e-6f) mb |= (1ull << b);  // 2^-17
    }
    if (mb) {  // rare: resolve borderline bits with exact reference divide
      unsigned long long r = mb;
      while (r) {
        int b = __ffsll(r) - 1; r &= r - 1;
        float4 bi = tbo[ibase + b];
        float ai = areas[ibase + b];
        float lx = fmaxf(bi.x, bj.x), ly = fmaxf(bi.y, bj.y);
        float rx = fminf(bi.z, bj.z), ry = fminf(bi.w, bj.w);
        float iw = fmaxf(rx - lx, 0.f), ih = fmaxf(ry - ly, 0.f);
        float inter = iw * ih;
        float denom = ai + aj - inter + 1e-9f;
        float iou = inter / denom;
        if (iou > 0.6f) m |= (1ull << b); else m &= ~(1ull << b);
      }
    }
    if (j >= PRE_K) m = 0ULL;
    else if (c == w) m &= (1ull << lane) - 1ull;   // rows i < j within chunk
    T[(size_t)p * 64 + lane] = m;
  }
  __syncthreads();

  // wave-0 ballot-fixpoint greedy (== sequential greedy scan)
  if (wave == 0) {
    float sval[16];
    #pragma unroll
    for (int k = 0; k < 16; ++k) sval[k] = sc[k * 64 + lane];
    unsigned removedbits = 0;
    #pragma unroll
    for (int c = 0; c < 16; ++c) {
      unsigned long long col = T[((c * (c + 1)) / 2 + c) * 64 + lane];
      unsigned long long sp = __ballot(sval[c] > 0.f);
      unsigned long long inc = __ballot(((removedbits >> c) & 1u) != 0u);
      unsigned long long K = sp & ~inc;
      unsigned long long kept = 0;
      for (int it = 0; it < 64; ++it) {
        unsigned long long Bsupp = __ballot((col & K) != 0ULL);
        unsigned long long Snew = K & ~Bsupp & ~kept;
        if (Snew == 0ULL) break;
        kept |= Snew;
        unsigned long long Bd = __ballot((col & kept) != 0ULL);
        K &= ~Bd;
      }
      if ((col & kept) != 0ULL) removedbits |= (1u << c);
      #pragma unroll
      for (int w = 0; w < 16; ++w) {
        if (w > c) {
          unsigned long long xw = T[((w * (w + 1)) / 2 + c) * 64 + lane];
          if ((xw & kept) != 0ULL) removedbits |= (1u << w);
        }
      }
      if (lane == 0) keptw[c] = kept;
    }
  }
  __syncthreads();

  // finalize: keep -> front (score desc already), zero-fill by index order
  bool inr = (tid < PRE_K);
  bool keep = inr && (((keptw[tid >> 6] >> (tid & 63)) & 1ull) != 0ull);
  sk[tid] = keep ? 1u : 0u;
  sz[tid] = (inr && !keep) ? 1u : 0u;
  __syncthreads();
  for (int ofs = 1; ofs < 1024; ofs <<= 1) {
    unsigned a = (tid >= ofs) ? sk[tid - ofs] : 0;
    unsigned b = (tid >= ofs) ? sz[tid - ofs] : 0;
    __syncthreads();
    sk[tid] += a; sz[tid] += b;
    __syncthreads();
  }
  int nk = (int)sk[1023];
  int slot = -1;
  if (inr) {
    if (keep) {
      int r = (int)sk[tid] - 1;
      if (r < POST_K) slot = r;
    } else {
      int r = nk + (int)sz[tid] - 1;
      if (r < POST_K) slot = r;
    }
  }
  if (slot >= 0) {
    size_t ob = ((size_t)n * POST_K + slot) * 4;
    float4 b4 = tb[tid];
    out[ob+0] = b4.x; out[ob+1] = b4.y; out[ob+2] = b4.z; out[ob+3] = b4.w;
    out[(size_t)NB*POST_K*4 + (size_t)n*POST_K + slot] = keep ? sc[tid] : 0.0f;
    out[(size_t)NB*POST_K*5 + (size_t)n*POST_K + slot] = (float)lb[tid];
  }
}

extern "C" void kernel_launch(void* const* d_in, const int* in_sizes, int n_in,
                              void* d_out, int out_size, void* d_ws, size_t ws_size,
                              hipStream_t stream) {
  char* w = (char*)d_ws;
  auto carve = [&](size_t bytes) { char* p = w; w += (bytes + 255) & ~(size_t)255; return p; };
  int* labels   = (int*)carve((size_t)NB * P_TOT * 4);
  float* boxes  = (float*)carve((size_t)NB * P_TOT * 16);
  unsigned long long* keys = (unsigned long long*)carve((size_t)NB * P_TOT * 8);

  const float* cls0 = (const float*)d_in[0];
  const float* reg0 = (const float*)d_in[1];
  const float* ctr0 = (const float*)d_in[2];
  const float* cls1 = (const float*)d_in[3];
  const float* reg1 = (const float*)d_in[4];
  const float* ctr1 = (const float*)d_in[5];
  const float* cls2 = (const float*)d_in[6];
  const float* reg2 = (const float*)d_in[7];
  const float* ctr2 = (const float*)d_in[8];
  const float* cls3 = (const float*)d_in[9];
  const float* reg3 = (const float*)d_in[10];
  const float* ctr3 = (const float*)d_in[11];
  const float* cls4 = (const float*)d_in[12];
  const float* reg4 = (const float*)d_in[13];
  const float* ctr4 = (const float*)d_in[14];

  dim3 dg((P4 + 63) / 64, NB);
  decode_kernel<<<dg, 256, 0, stream>>>(cls0, reg0, ctr0, cls1, reg1, ctr1,
                                        cls2, reg2, ctr2, cls3, reg3, ctr3,
                                        cls4, reg4, ctr4,
                                        labels, boxes, keys);
  tail_kernel<<<NB, 1024, 0, stream>>>(keys, boxes, labels, (float*)d_out);
}

// Round 18
// 67.539 us; speedup vs baseline: 1.9267x; 1.9267x over previous
//
#include <hip/hip_runtime.h>
#include <stdint.h>

#pragma clang fp contract(off)

#define NB 16
#define NC 80
#define P_TOT 17064
#define P4 (P_TOT / 4)
#define PRE_K 1000
#define POST_K 100

__device__ __forceinline__ float sigmoidf_(float x) {
  return 1.0f / (1.0f + expf(-x));
}

// Decode (monotonicity trick: argmax over classes == argmax over raw logits;
// exact score computed once for the winner). 8-lane class split: lane t8 scans
// 10 classes, all 10 float4 loads batched into registers. 3-step shfl_xor
// reduce with lower-label tie-break (exact first-max; ranges ascend with t8).
// Lanes t8<4 each decode their own location (arithmetic verbatim).
__global__ __launch_bounds__(256) void decode_kernel(
    const float* __restrict__ cls0, const float* __restrict__ reg0, const float* __restrict__ ctr0,
    const float* __restrict__ cls1, const float* __restrict__ reg1, const float* __restrict__ ctr1,
    const float* __restrict__ cls2, const float* __restrict__ reg2, const float* __restrict__ ctr2,
    const float* __restrict__ cls3, const float* __restrict__ reg3, const float* __restrict__ ctr3,
    const float* __restrict__ cls4, const float* __restrict__ reg4, const float* __restrict__ ctr4,
    int* __restrict__ labels, float* __restrict__ boxes,
    unsigned long long* __restrict__ keys)
{
  int quad = blockIdx.x * 32 + (threadIdx.x >> 3);
  int t8 = threadIdx.x & 7;
  int n = blockIdx.y;
  if (quad >= P4) return;
  int p0 = quad * 4;
  int off, wsh, hw; float stride; const float *cls, *reg, *ctr;
  if (p0 < 12800)      { off = 0;     wsh = 7; hw = 12800; stride = 8.f;   cls = cls0; reg = reg0; ctr = ctr0; }
  else if (p0 < 16000) { off = 12800; wsh = 6; hw = 3200;  stride = 16.f;  cls = cls1; reg = reg1; ctr = ctr1; }
  else if (p0 < 16800) { off = 16000; wsh = 5; hw = 800;   stride = 32.f;  cls = cls2; reg = reg2; ctr = ctr2; }
  else if (p0 < 17008) { off = 16800; wsh = 4; hw = 208;   stride = 64.f;  cls = cls3; reg = reg3; ctr = ctr3; }
  else                 { off = 17008; wsh = 3; hw = 56;    stride = 128.f; cls = cls4; reg = reg4; ctr = ctr4; }
  int loc0 = p0 - off;
  int y = loc0 >> wsh;
  int x0 = loc0 & ((1 << wsh) - 1);
  float py = (float)y * stride + 0.5f * stride;

  int c0 = t8 * 10;
  const float* cptr = cls + (size_t)n * NC * hw + (size_t)c0 * hw + loc0;
  float4 cv[10];
  #pragma unroll
  for (int k = 0; k < 10; ++k)
    cv[k] = *reinterpret_cast<const float4*>(cptr + (size_t)k * hw);

  float best[4] = { -3.4e38f, -3.4e38f, -3.4e38f, -3.4e38f };
  int bl[4] = { c0, c0, c0, c0 };
  #pragma unroll
  for (int k = 0; k < 10; ++k) {
    int c = c0 + k;
    if (cv[k].x > best[0]) { best[0] = cv[k].x; bl[0] = c; }
    if (cv[k].y > best[1]) { best[1] = cv[k].y; bl[1] = c; }
    if (cv[k].z > best[2]) { best[2] = cv[k].z; bl[2] = c; }
    if (cv[k].w > best[3]) { best[3] = cv[k].w; bl[3] = c; }
  }
  #pragma unroll
  for (int e = 0; e < 4; ++e) {
    #pragma unroll
    for (int d = 1; d <= 4; d <<= 1) {
      float ob = __shfl_xor(best[e], d);
      int ol = __shfl_xor(bl[e], d);
      if (ob > best[e] || (ob == best[e] && ol < bl[e])) { best[e] = ob; bl[e] = ol; }
    }
  }
  if (t8 >= 4) return;

  int e = t8;
  int loce = loc0 + e;
  float sctr_e = sigmoidf_(ctr[(size_t)n * hw + loce]);
  const float* rbase = reg + (size_t)n * 4 * hw + loce;
  float dl = rbase[0];
  float dt = rbase[(size_t)hw];
  float dr = rbase[(size_t)2 * hw];
  float db = rbase[(size_t)3 * hw];

  float s = sqrtf(sigmoidf_(best[e]) * sctr_e);
  float val = (s > 0.05f) ? s : 0.0f;
  float px = (float)(x0 + e) * stride + 0.5f * stride;
  float x1 = fminf(fmaxf(px - dl, 0.f), 1024.f);
  float y1 = fminf(fmaxf(py - dt, 0.f), 800.f);
  float x2 = fminf(fmaxf(px + dr, 0.f), 1024.f);
  float y2 = fminf(fmaxf(py + db, 0.f), 800.f);

  size_t o = (size_t)n * P_TOT + p0 + e;
  labels[o] = bl[e];
  *reinterpret_cast<float4*>(boxes + 4 * o) = make_float4(x1, y1, x2, y2);
  keys[o] = ((unsigned long long)__float_as_uint(val) << 32)
          | (unsigned long long)(0xFFFFFFFFu - (unsigned)(p0 + e));
}

// Fully-fused top-k, SORT-FREE. One block per batch.
// Scores in [0,1] -> key>>48 < 0x4000 -> 16384-bin u32 LDS hist.
__global__ __launch_bounds__(1024) void topgather_kernel(
    const unsigned long long* __restrict__ keys,
    const float* __restrict__ boxes, const int* __restrict__ labels,
    float* __restrict__ tboxes, float* __restrict__ tscores, int* __restrict__ tlabels)
{
  int n = blockIdx.x;
  int tid = threadIdx.x;
  int wave = tid >> 6;
  int lane = tid & 63;
  __shared__ unsigned hist[16384];
  __shared__ unsigned Wt[16], Wsuf[16];
  __shared__ unsigned s_d, s_M;
  __shared__ unsigned long long skey[2048];

  for (int i = tid; i < 16384; i += 1024) hist[i] = 0;
  __syncthreads();
  const unsigned long long* bk = keys + (size_t)n * P_TOT;
  for (int p = tid; p < P_TOT; p += 1024) {
    unsigned h = (unsigned)(bk[p] >> 48);   // < 16384 guaranteed
    atomicAdd(&hist[h], 1u);
  }
  __syncthreads();

  unsigned bvs[16];
  unsigned ssum = 0;
  #pragma unroll
  for (int q = 0; q < 16; ++q) { bvs[q] = hist[tid * 16 + q]; ssum += bvs[q]; }
  unsigned v = ssum;
  #pragma unroll
  for (int d = 1; d < 64; d <<= 1) {
    unsigned t = __shfl_down(v, d);
    if (lane + d < 64) v += t;
  }
  if (lane == 0) Wt[wave] = v;
  __syncthreads();
  if (wave == 0 && lane < 16) {
    unsigned wv = Wt[lane];
    unsigned own = wv;
    #pragma unroll
    for (int d = 1; d < 16; d <<= 1) {
      unsigned t = __shfl_down(wv, d);
      if (lane + d < 16) wv += t;
    }
    Wsuf[lane] = wv - own;
  }
  __syncthreads();
  unsigned At = v + Wsuf[wave];
  unsigned An = At - ssum;
  if (At >= PRE_K && An < PRE_K) {   // unique crossing strip (monotone)
    unsigned cum = An;
    int d = tid * 16;
    unsigned M = 0;
    bool done = false;
    #pragma unroll
    for (int b = 15; b >= 0; --b) {
      if (!done) {
        cum += bvs[b];
        if (cum >= PRE_K) { d = tid * 16 + b; M = cum; done = true; }
      }
    }
    s_d = (unsigned)d;
    s_M = M;
  }
  __syncthreads();
  unsigned dsel = s_d;
  {
    unsigned cum = An;
    #pragma unroll
    for (int b = 15; b >= 0; --b) {
      unsigned h = (unsigned)(tid * 16 + b);
      if (h >= dsel) hist[h] = cum << 16;
      cum += bvs[b];
    }
  }
  __syncthreads();
  for (int p = tid; p < P_TOT; p += 1024) {
    unsigned long long k = bk[p];
    unsigned h = (unsigned)(k >> 48);
    if (h >= dsel) {
      unsigned old = atomicAdd(&hist[h], 1u);
      unsigned slot = (old >> 16) + (old & 0xFFFFu);
      if (slot < 2048) skey[slot] = k;
    }
  }
  __syncthreads();
  unsigned Mcap = s_M < 2048u ? s_M : 2048u;
  #pragma unroll
  for (int e = 0; e < 2; ++e) {
    unsigned sidx = (unsigned)tid + e * 1024;
    if (sidx < Mcap) {
      unsigned long long k = skey[sidx];
      unsigned h = (unsigned)(k >> 48);
      unsigned info = hist[h];
      unsigned start = info >> 16;
      unsigned end = start + (info & 0xFFFFu);
      if (end > 2048u) end = 2048u;
      unsigned rank = 0;
      for (unsigned q = start; q < end; ++q)
        rank += (skey[q] > k) ? 1u : 0u;
      unsigned pos = start + rank;
      if (pos < PRE_K) {
        unsigned idx = 0xFFFFFFFFu - (unsigned)(k & 0xFFFFFFFFu);
        float sc = __uint_as_float((unsigned)(k >> 32));
        size_t src = (size_t)n * P_TOT + idx;
        size_t dst = (size_t)n * PRE_K + pos;
        tscores[dst] = sc;
        tlabels[dst] = labels[src];
        *reinterpret_cast<float4*>(tboxes + 4 * dst) =
            *reinterpret_cast<const float4*>(boxes + 4 * src);
      }
    }
  }
}

// COLUMN-major suppression on a 2048-block grid (full-chip parallel).
// Divide-free guard-band; decisions bit-identical to fl(inter/denom)>0.6f.
__global__ __launch_bounds__(128) void iou_kernel(
    const float* __restrict__ tboxes, const int* __restrict__ tlabels,
    unsigned long long* __restrict__ colsupp)
{
  int jb = blockIdx.x, w = blockIdx.y, n = blockIdx.z;
  int tid = threadIdx.x;
  int j = jb * 128 + tid;
  bool jvalid = (j < PRE_K);
  int ibase = w * 64;

  if (ibase >= jb * 128 + 128) {
    if (jvalid) colsupp[((size_t)n * PRE_K + j) * 16 + w] = 0ULL;
    return;
  }

  __shared__ float4 sb[64];
  __shared__ float sa[64];
  if (tid < 64) {
    int i = ibase + tid;
    float4 v = make_float4(0.f, 0.f, 0.f, 0.f);
    if (i < PRE_K) {
      const float* b = tboxes + ((size_t)n * PRE_K + i) * 4;
      float offv = (float)tlabels[(size_t)n * PRE_K + i] * 4096.0f;
      v = make_float4(b[0] + offv, b[1] + offv, b[2] + offv, b[3] + offv);
    }
    sb[tid] = v;
    sa[tid] = (v.z - v.x) * (v.w - v.y);
  }
  __syncthreads();

  float4 bj = make_float4(0.f, 0.f, 0.f, 0.f);
  if (jvalid) {
    const float* b = tboxes + ((size_t)n * PRE_K + j) * 4;
    float offv = (float)tlabels[(size_t)n * PRE_K + j] * 4096.0f;
    bj = make_float4(b[0] + offv, b[1] + offv, b[2] + offv, b[3] + offv);
  }
  float aj = (bj.z - bj.x) * (bj.w - bj.y);

  unsigned long long m = 0, mb = 0;
  #pragma unroll
  for (int b = 0; b < 64; ++b) {
    float4 bi = sb[b];
    float ai = sa[b];
    float lx = fmaxf(bi.x, bj.x), ly = fmaxf(bi.y, bj.y);
    float rx = fminf(bi.z, bj.z), ry = fminf(bi.w, bj.w);
    float iw = fmaxf(rx - lx, 0.f), ih = fmaxf(ry - ly, 0.f);
    float inter = iw * ih;
    float denom = ai + aj - inter + 1e-9f;
    float t = inter - 0.6f * denom;
    if (t > 0.f) m |= (1ull << b);
    if (fabsf(t) <= denom * 7.62939453125e-6f) mb |= (1ull << b);  // 2^-17
  }
  if (mb) {
    unsigned long long r = mb;
    while (r) {
      int b = __ffsll(r) - 1; r &= r - 1;
      float4 bi = sb[b];
      float ai = sa[b];
      float lx = fmaxf(bi.x, bj.x), ly = fmaxf(bi.y, bj.y);
      float rx = fminf(bi.z, bj.z), ry = fminf(bi.w, bj.w);
      float iw = fmaxf(rx - lx, 0.f), ih = fmaxf(ry - ly, 0.f);
      float inter = iw * ih;
      float denom = ai + aj - inter + 1e-9f;
      float iou = inter / denom;
      if (iou > 0.6f) m |= (1ull << b); else m &= ~(1ull << b);
    }
  }
  unsigned long long tri;
  if (ibase >= j) tri = 0ULL;
  else if (j - ibase >= 64) tri = ~0ULL;
  else tri = (1ull << (j - ibase)) - 1ull;
  m &= tri;
  if (jvalid) colsupp[((size_t)n * PRE_K + j) * 16 + w] = m;
}

// Fused greedy + finalize with LDS-staged suppression triangle (no spills).
__global__ __launch_bounds__(1024) void greedyfin_kernel(
    const unsigned long long* __restrict__ colsupp, const float* __restrict__ tscores,
    const float* __restrict__ tboxes, const int* __restrict__ tlabels,
    float* __restrict__ out)
{
  int n = blockIdx.x;
  int tid = threadIdx.x;
  int wave = tid >> 6;
  int lane = tid & 63;
  __shared__ unsigned long long T[136 * 64];   // tri(c<=w): T[(w*(w+1)/2+c)*64+l]
  __shared__ unsigned long long keptw[16];

  {
    int wq = wave;
    int j = wq * 64 + lane;
    int base = (wq * (wq + 1)) / 2;
    if (j < PRE_K) {
      const unsigned long long* C = colsupp + ((size_t)n * PRE_K + j) * 16;
      for (int c = 0; c <= wq; ++c) T[(base + c) * 64 + lane] = C[c];
    } else {
      for (int c = 0; c <= wq; ++c) T[(base + c) * 64 + lane] = 0ULL;
    }
  }
  __syncthreads();

  if (wave == 0) {
    const float* sc = tscores + (size_t)n * PRE_K;
    float sval[16];
    #pragma unroll
    for (int k = 0; k < 16; ++k) {
      int j = k * 64 + lane;
      sval[k] = (j < PRE_K) ? sc[j] : 0.f;
    }
    unsigned removedbits = 0;
    #pragma unroll
    for (int c = 0; c < 16; ++c) {
      unsigned long long col = T[((c * (c + 1)) / 2 + c) * 64 + lane];
      unsigned long long sp = __ballot(sval[c] > 0.f);
      unsigned long long inc = __ballot(((removedbits >> c) & 1u) != 0u);
      unsigned long long K = sp & ~inc;
      unsigned long long kept = 0;
      for (int it = 0; it < 64; ++it) {
        unsigned long long Bsupp = __ballot((col & K) != 0ULL);
        unsigned long long Snew = K & ~Bsupp & ~kept;
        if (Snew == 0ULL) break;
        kept |= Snew;
        unsigned long long Bd = __ballot((col & kept) != 0ULL);
        K &= ~Bd;
      }
      if ((col & kept) != 0ULL) removedbits |= (1u << c);
      #pragma unroll
      for (int w = 0; w < 16; ++w) {
        if (w > c) {
          unsigned long long xw = T[((w * (w + 1)) / 2 + c) * 64 + lane];
          if ((xw & kept) != 0ULL) removedbits |= (1u << w);
        }
      }
      if (lane == 0) keptw[c] = kept;
    }
  }
  __syncthreads();

  __shared__ unsigned sk[1024];
  __shared__ unsigned sz[1024];
  bool inr = (tid < PRE_K);
  bool keep = inr && (((keptw[tid >> 6] >> (tid & 63)) & 1ull) != 0ull);
  sk[tid] = keep ? 1u : 0u;
  sz[tid] = (inr && !keep) ? 1u : 0u;
  __syncthreads();
  for (int ofs = 1; ofs < 1024; ofs <<= 1) {
    unsigned a = (tid >= ofs) ? sk[tid - ofs] : 0;
    unsigned b = (tid >= ofs) ? sz[tid - ofs] : 0;
    __syncthreads();
    sk[tid] += a; sz[tid] += b;
    __syncthreads();
  }
  int nk = (int)sk[1023];
  int slot = -1;
  if (inr) {
    if (keep) {
      int r = (int)sk[tid] - 1;
      if (r < POST_K) slot = r;
    } else {
      int r = nk + (int)sz[tid] - 1;
      if (r < POST_K) slot = r;
    }
  }
  if (slot >= 0) {
    size_t src = (size_t)n * PRE_K + tid;
    size_t ob = ((size_t)n * POST_K + slot) * 4;
    out[ob+0] = tboxes[4*src+0];
    out[ob+1] = tboxes[4*src+1];
    out[ob+2] = tboxes[4*src+2];
    out[ob+3] = tboxes[4*src+3];
    out[(size_t)NB*POST_K*4 + (size_t)n*POST_K + slot] = keep ? tscores[src] : 0.0f;
    out[(size_t)NB*POST_K*5 + (size_t)n*POST_K + slot] = (float)tlabels[src];
  }
}

extern "C" void kernel_launch(void* const* d_in, const int* in_sizes, int n_in,
                              void* d_out, int out_size, void* d_ws, size_t ws_size,
                              hipStream_t stream) {
  char* w = (char*)d_ws;
  auto carve = [&](size_t bytes) { char* p = w; w += (bytes + 255) & ~(size_t)255; return p; };
  int* labels   = (int*)carve((size_t)NB * P_TOT * 4);
  float* boxes  = (float*)carve((size_t)NB * P_TOT * 16);
  unsigned long long* keys = (unsigned long long*)carve((size_t)NB * P_TOT * 8);
  unsigned long long* colsupp = (unsigned long long*)carve((size_t)NB * PRE_K * 16 * 8);
  float* tboxes  = (float*)carve((size_t)NB * PRE_K * 16);
  float* tscores = (float*)carve((size_t)NB * PRE_K * 4);
  int* tlabels   = (int*)carve((size_t)NB * PRE_K * 4);

  const float* cls0 = (const float*)d_in[0];
  const float* reg0 = (const float*)d_in[1];
  const float* ctr0 = (const float*)d_in[2];
  const float* cls1 = (const float*)d_in[3];
  const float* reg1 = (const float*)d_in[4];
  const float* ctr1 = (const float*)d_in[5];
  const float* cls2 = (const float*)d_in[6];
  const float* reg2 = (const float*)d_in[7];
  const float* ctr2 = (const float*)d_in[8];
  const float* cls3 = (const float*)d_in[9];
  const float* reg3 = (const float*)d_in[10];
  const float* ctr3 = (const float*)d_in[11];
  const float* cls4 = (const float*)d_in[12];
  const float* reg4 = (const float*)d_in[13];
  const float* ctr4 = (const float*)d_in[14];

  dim3 dg((P4 + 31) / 32, NB);
  decode_kernel<<<dg, 256, 0, stream>>>(cls0, reg0, ctr0, cls1, reg1, ctr1,
                                        cls2, reg2, ctr2, cls3, reg3, ctr3,
                                        cls4, reg4, ctr4,
                                        labels, boxes, keys);
  topgather_kernel<<<NB, 1024, 0, stream>>>(keys, boxes, labels,
                                            tboxes, tscores, tlabels);
  dim3 gi(8, 16, NB);
  iou_kernel<<<gi, 128, 0, stream>>>(tboxes, tlabels, colsupp);
  greedyfin_kernel<<<NB, 1024, 0, stream>>>(colsupp, tscores, tboxes, tlabels, (float*)d_out);
}

// Round 19
// 67.395 us; speedup vs baseline: 1.9308x; 1.0021x over previous
//
#include <hip/hip_runtime.h>
#include <stdint.h>

#pragma clang fp contract(off)

#define NB 16
#define NC 80
#define P_TOT 17064
#define P4 (P_TOT / 4)
#define PRE_K 1000
#define POST_K 100

__device__ __forceinline__ float sigmoidf_(float x) {
  return 1.0f / (1.0f + expf(-x));
}

// Decode (monotonicity trick: argmax over classes == argmax over raw logits;
// exact score computed once for the winner). 8-lane class split: lane t8 scans
// 10 classes. The asm fences force all 10 float4 loads LIVE simultaneously
// (compiler otherwise re-fuses load+compare -> ~5 outstanding loads; round-11
// profile showed VGPR_Count=32 proving the "batched" array was serialized).
__global__ __launch_bounds__(256, 4) void decode_kernel(
    const float* __restrict__ cls0, const float* __restrict__ reg0, const float* __restrict__ ctr0,
    const float* __restrict__ cls1, const float* __restrict__ reg1, const float* __restrict__ ctr1,
    const float* __restrict__ cls2, const float* __restrict__ reg2, const float* __restrict__ ctr2,
    const float* __restrict__ cls3, const float* __restrict__ reg3, const float* __restrict__ ctr3,
    const float* __restrict__ cls4, const float* __restrict__ reg4, const float* __restrict__ ctr4,
    int* __restrict__ labels, float* __restrict__ boxes,
    unsigned long long* __restrict__ keys)
{
  int quad = blockIdx.x * 32 + (threadIdx.x >> 3);
  int t8 = threadIdx.x & 7;
  int n = blockIdx.y;
  if (quad >= P4) return;
  int p0 = quad * 4;
  int off, wsh, hw; float stride; const float *cls, *reg, *ctr;
  if (p0 < 12800)      { off = 0;     wsh = 7; hw = 12800; stride = 8.f;   cls = cls0; reg = reg0; ctr = ctr0; }
  else if (p0 < 16000) { off = 12800; wsh = 6; hw = 3200;  stride = 16.f;  cls = cls1; reg = reg1; ctr = ctr1; }
  else if (p0 < 16800) { off = 16000; wsh = 5; hw = 800;   stride = 32.f;  cls = cls2; reg = reg2; ctr = ctr2; }
  else if (p0 < 17008) { off = 16800; wsh = 4; hw = 208;   stride = 64.f;  cls = cls3; reg = reg3; ctr = ctr3; }
  else                 { off = 17008; wsh = 3; hw = 56;    stride = 128.f; cls = cls4; reg = reg4; ctr = ctr4; }
  int loc0 = p0 - off;
  int y = loc0 >> wsh;
  int x0 = loc0 & ((1 << wsh) - 1);
  float py = (float)y * stride + 0.5f * stride;

  int c0 = t8 * 10;
  const float* cptr = cls + (size_t)n * NC * hw + (size_t)c0 * hw + loc0;
  float4 cv[10];
  #pragma unroll
  for (int k = 0; k < 10; ++k)
    cv[k] = *reinterpret_cast<const float4*>(cptr + (size_t)k * hw);
  // force ALL loads issued & live before the compare chain
  #pragma unroll
  for (int k = 0; k < 10; ++k)
    asm volatile("" : "+v"(cv[k].x), "+v"(cv[k].y), "+v"(cv[k].z), "+v"(cv[k].w));

  float best[4] = { -3.4e38f, -3.4e38f, -3.4e38f, -3.4e38f };
  int bl[4] = { c0, c0, c0, c0 };
  #pragma unroll
  for (int k = 0; k < 10; ++k) {
    int c = c0 + k;
    if (cv[k].x > best[0]) { best[0] = cv[k].x; bl[0] = c; }
    if (cv[k].y > best[1]) { best[1] = cv[k].y; bl[1] = c; }
    if (cv[k].z > best[2]) { best[2] = cv[k].z; bl[2] = c; }
    if (cv[k].w > best[3]) { best[3] = cv[k].w; bl[3] = c; }
  }
  #pragma unroll
  for (int e = 0; e < 4; ++e) {
    #pragma unroll
    for (int d = 1; d <= 4; d <<= 1) {
      float ob = __shfl_xor(best[e], d);
      int ol = __shfl_xor(bl[e], d);
      if (ob > best[e] || (ob == best[e] && ol < bl[e])) { best[e] = ob; bl[e] = ol; }
    }
  }
  if (t8 >= 4) return;

  int e = t8;
  int loce = loc0 + e;
  float sctr_e = sigmoidf_(ctr[(size_t)n * hw + loce]);
  const float* rbase = reg + (size_t)n * 4 * hw + loce;
  float dl = rbase[0];
  float dt = rbase[(size_t)hw];
  float dr = rbase[(size_t)2 * hw];
  float db = rbase[(size_t)3 * hw];

  float s = sqrtf(sigmoidf_(best[e]) * sctr_e);
  float val = (s > 0.05f) ? s : 0.0f;
  float px = (float)(x0 + e) * stride + 0.5f * stride;
  float x1 = fminf(fmaxf(px - dl, 0.f), 1024.f);
  float y1 = fminf(fmaxf(py - dt, 0.f), 800.f);
  float x2 = fminf(fmaxf(px + dr, 0.f), 1024.f);
  float y2 = fminf(fmaxf(py + db, 0.f), 800.f);

  size_t o = (size_t)n * P_TOT + p0 + e;
  labels[o] = bl[e];
  *reinterpret_cast<float4*>(boxes + 4 * o) = make_float4(x1, y1, x2, y2);
  keys[o] = ((unsigned long long)__float_as_uint(val) << 32)
          | (unsigned long long)(0xFFFFFFFFu - (unsigned)(p0 + e));
}

// Fully-fused top-k, SORT-FREE. One block per batch.
// Scores in [0,1] -> key>>48 < 0x4000 -> 16384-bin u32 LDS hist.
__global__ __launch_bounds__(1024) void topgather_kernel(
    const unsigned long long* __restrict__ keys,
    const float* __restrict__ boxes, const int* __restrict__ labels,
    float* __restrict__ tboxes, float* __restrict__ tscores, int* __restrict__ tlabels)
{
  int n = blockIdx.x;
  int tid = threadIdx.x;
  int wave = tid >> 6;
  int lane = tid & 63;
  __shared__ unsigned hist[16384];
  __shared__ unsigned Wt[16], Wsuf[16];
  __shared__ unsigned s_d, s_M;
  __shared__ unsigned long long skey[2048];

  for (int i = tid; i < 16384; i += 1024) hist[i] = 0;
  __syncthreads();
  const unsigned long long* bk = keys + (size_t)n * P_TOT;
  for (int p = tid; p < P_TOT; p += 1024) {
    unsigned h = (unsigned)(bk[p] >> 48);   // < 16384 guaranteed
    atomicAdd(&hist[h], 1u);
  }
  __syncthreads();

  unsigned bvs[16];
  unsigned ssum = 0;
  #pragma unroll
  for (int q = 0; q < 16; ++q) { bvs[q] = hist[tid * 16 + q]; ssum += bvs[q]; }
  unsigned v = ssum;
  #pragma unroll
  for (int d = 1; d < 64; d <<= 1) {
    unsigned t = __shfl_down(v, d);
    if (lane + d < 64) v += t;
  }
  if (lane == 0) Wt[wave] = v;
  __syncthreads();
  if (wave == 0 && lane < 16) {
    unsigned wv = Wt[lane];
    unsigned own = wv;
    #pragma unroll
    for (int d = 1; d < 16; d <<= 1) {
      unsigned t = __shfl_down(wv, d);
      if (lane + d < 16) wv += t;
    }
    Wsuf[lane] = wv - own;
  }
  __syncthreads();
  unsigned At = v + Wsuf[wave];
  unsigned An = At - ssum;
  if (At >= PRE_K && An < PRE_K) {   // unique crossing strip (monotone)
    unsigned cum = An;
    int d = tid * 16;
    unsigned M = 0;
    bool done = false;
    #pragma unroll
    for (int b = 15; b >= 0; --b) {
      if (!done) {
        cum += bvs[b];
        if (cum >= PRE_K) { d = tid * 16 + b; M = cum; done = true; }
      }
    }
    s_d = (unsigned)d;
    s_M = M;
  }
  __syncthreads();
  unsigned dsel = s_d;
  {
    unsigned cum = An;
    #pragma unroll
    for (int b = 15; b >= 0; --b) {
      unsigned h = (unsigned)(tid * 16 + b);
      if (h >= dsel) hist[h] = cum << 16;
      cum += bvs[b];
    }
  }
  __syncthreads();
  for (int p = tid; p < P_TOT; p += 1024) {
    unsigned long long k = bk[p];
    unsigned h = (unsigned)(k >> 48);
    if (h >= dsel) {
      unsigned old = atomicAdd(&hist[h], 1u);
      unsigned slot = (old >> 16) + (old & 0xFFFFu);
      if (slot < 2048) skey[slot] = k;
    }
  }
  __syncthreads();
  unsigned Mcap = s_M < 2048u ? s_M : 2048u;
  #pragma unroll
  for (int e = 0; e < 2; ++e) {
    unsigned sidx = (unsigned)tid + e * 1024;
    if (sidx < Mcap) {
      unsigned long long k = skey[sidx];
      unsigned h = (unsigned)(k >> 48);
      unsigned info = hist[h];
      unsigned start = info >> 16;
      unsigned end = start + (info & 0xFFFFu);
      if (end > 2048u) end = 2048u;
      unsigned rank = 0;
      for (unsigned q = start; q < end; ++q)
        rank += (skey[q] > k) ? 1u : 0u;
      unsigned pos = start + rank;
      if (pos < PRE_K) {
        unsigned idx = 0xFFFFFFFFu - (unsigned)(k & 0xFFFFFFFFu);
        float sc = __uint_as_float((unsigned)(k >> 32));
        size_t src = (size_t)n * P_TOT + idx;
        size_t dst = (size_t)n * PRE_K + pos;
        tscores[dst] = sc;
        tlabels[dst] = labels[src];
        *reinterpret_cast<float4*>(tboxes + 4 * dst) =
            *reinterpret_cast<const float4*>(boxes + 4 * src);
      }
    }
  }
}

// COLUMN-major suppression on a 2048-block grid (full-chip parallel).
// Divide-free guard-band; decisions bit-identical to fl(inter/denom)>0.6f.
__global__ __launch_bounds__(128) void iou_kernel(
    const float* __restrict__ tboxes, const int* __restrict__ tlabels,
    unsigned long long* __restrict__ colsupp)
{
  int jb = blockIdx.x, w = blockIdx.y, n = blockIdx.z;
  int tid = threadIdx.x;
  int j = jb * 128 + tid;
  bool jvalid = (j < PRE_K);
  int ibase = w * 64;

  if (ibase >= jb * 128 + 128) {
    if (jvalid) colsupp[((size_t)n * PRE_K + j) * 16 + w] = 0ULL;
    return;
  }

  __shared__ float4 sb[64];
  __shared__ float sa[64];
  if (tid < 64) {
    int i = ibase + tid;
    float4 v = make_float4(0.f, 0.f, 0.f, 0.f);
    if (i < PRE_K) {
      const float* b = tboxes + ((size_t)n * PRE_K + i) * 4;
      float offv = (float)tlabels[(size_t)n * PRE_K + i] * 4096.0f;
      v = make_float4(b[0] + offv, b[1] + offv, b[2] + offv, b[3] + offv);
    }
    sb[tid] = v;
    sa[tid] = (v.z - v.x) * (v.w - v.y);
  }
  __syncthreads();

  float4 bj = make_float4(0.f, 0.f, 0.f, 0.f);
  if (jvalid) {
    const float* b = tboxes + ((size_t)n * PRE_K + j) * 4;
    float offv = (float)tlabels[(size_t)n * PRE_K + j] * 4096.0f;
    bj = make_float4(b[0] + offv, b[1] + offv, b[2] + offv, b[3] + offv);
  }
  float aj = (bj.z - bj.x) * (bj.w - bj.y);

  unsigned long long m = 0, mb = 0;
  #pragma unroll
  for (int b = 0; b < 64; ++b) {
    float4 bi = sb[b];
    float ai = sa[b];
    float lx = fmaxf(bi.x, bj.x), ly = fmaxf(bi.y, bj.y);
    float rx = fminf(bi.z, bj.z), ry = fminf(bi.w, bj.w);
    float iw = fmaxf(rx - lx, 0.f), ih = fmaxf(ry - ly, 0.f);
    float inter = iw * ih;
    float denom = ai + aj - inter + 1e-9f;
    float t = inter - 0.6f * denom;
    if (t > 0.f) m |= (1ull << b);
    if (fabsf(t) <= denom * 7.62939453125e-6f) mb |= (1ull << b);  // 2^-17
  }
  if (mb) {
    unsigned long long r = mb;
    while (r) {
      int b = __ffsll(r) - 1; r &= r - 1;
      float4 bi = sb[b];
      float ai = sa[b];
      float lx = fmaxf(bi.x, bj.x), ly = fmaxf(bi.y, bj.y);
      float rx = fminf(bi.z, bj.z), ry = fminf(bi.w, bj.w);
      float iw = fmaxf(rx - lx, 0.f), ih = fmaxf(ry - ly, 0.f);
      float inter = iw * ih;
      float denom = ai + aj - inter + 1e-9f;
      float iou = inter / denom;
      if (iou > 0.6f) m |= (1ull << b); else m &= ~(1ull << b);
    }
  }
  unsigned long long tri;
  if (ibase >= j) tri = 0ULL;
  else if (j - ibase >= 64) tri = ~0ULL;
  else tri = (1ull << (j - ibase)) - 1ull;
  m &= tri;
  if (jvalid) colsupp[((size_t)n * PRE_K + j) * 16 + w] = m;
}

// Fused greedy + finalize with LDS-staged suppression triangle (no spills).
__global__ __launch_bounds__(1024) void greedyfin_kernel(
    const unsigned long long* __restrict__ colsupp, const float* __restrict__ tscores,
    const float* __restrict__ tboxes, const int* __restrict__ tlabels,
    float* __restrict__ out)
{
  int n = blockIdx.x;
  int tid = threadIdx.x;
  int wave = tid >> 6;
  int lane = tid & 63;
  __shared__ unsigned long long T[136 * 64];   // tri(c<=w): T[(w*(w+1)/2+c)*64+l]
  __shared__ unsigned long long keptw[16];

  {
    int wq = wave;
    int j = wq * 64 + lane;
    int base = (wq * (wq + 1)) / 2;
    if (j < PRE_K) {
      const unsigned long long* C = colsupp + ((size_t)n * PRE_K + j) * 16;
      for (int c = 0; c <= wq; ++c) T[(base + c) * 64 + lane] = C[c];
    } else {
      for (int c = 0; c <= wq; ++c) T[(base + c) * 64 + lane] = 0ULL;
    }
  }
  __syncthreads();

  if (wave == 0) {
    const float* sc = tscores + (size_t)n * PRE_K;
    float sval[16];
    #pragma unroll
    for (int k = 0; k < 16; ++k) {
      int j = k * 64 + lane;
      sval[k] = (j < PRE_K) ? sc[j] : 0.f;
    }
    unsigned removedbits = 0;
    #pragma unroll
    for (int c = 0; c < 16; ++c) {
      unsigned long long col = T[((c * (c + 1)) / 2 + c) * 64 + lane];
      unsigned long long sp = __ballot(sval[c] > 0.f);
      unsigned long long inc = __ballot(((removedbits >> c) & 1u) != 0u);
      unsigned long long K = sp & ~inc;
      unsigned long long kept = 0;
      for (int it = 0; it < 64; ++it) {
        unsigned long long Bsupp = __ballot((col & K) != 0ULL);
        unsigned long long Snew = K & ~Bsupp & ~kept;
        if (Snew == 0ULL) break;
        kept |= Snew;
        unsigned long long Bd = __ballot((col & kept) != 0ULL);
        K &= ~Bd;
      }
      if ((col & kept) != 0ULL) removedbits |= (1u << c);
      #pragma unroll
      for (int w = 0; w < 16; ++w) {
        if (w > c) {
          unsigned long long xw = T[((w * (w + 1)) / 2 + c) * 64 + lane];
          if ((xw & kept) != 0ULL) removedbits |= (1u << w);
        }
      }
      if (lane == 0) keptw[c] = kept;
    }
  }
  __syncthreads();

  __shared__ unsigned sk[1024];
  __shared__ unsigned sz[1024];
  bool inr = (tid < PRE_K);
  bool keep = inr && (((keptw[tid >> 6] >> (tid & 63)) & 1ull) != 0ull);
  sk[tid] = keep ? 1u : 0u;
  sz[tid] = (inr && !keep) ? 1u : 0u;
  __syncthreads();
  for (int ofs = 1; ofs < 1024; ofs <<= 1) {
    unsigned a = (tid >= ofs) ? sk[tid - ofs] : 0;
    unsigned b = (tid >= ofs) ? sz[tid - ofs] : 0;
    __syncthreads();
    sk[tid] += a; sz[tid] += b;
    __syncthreads();
  }
  int nk = (int)sk[1023];
  int slot = -1;
  if (inr) {
    if (keep) {
      int r = (int)sk[tid] - 1;
      if (r < POST_K) slot = r;
    } else {
      int r = nk + (int)sz[tid] - 1;
      if (r < POST_K) slot = r;
    }
  }
  if (slot >= 0) {
    size_t src = (size_t)n * PRE_K + tid;
    size_t ob = ((size_t)n * POST_K + slot) * 4;
    out[ob+0] = tboxes[4*src+0];
    out[ob+1] = tboxes[4*src+1];
    out[ob+2] = tboxes[4*src+2];
    out[ob+3] = tboxes[4*src+3];
    out[(size_t)NB*POST_K*4 + (size_t)n*POST_K + slot] = keep ? tscores[src] : 0.0f;
    out[(size_t)NB*POST_K*5 + (size_t)n*POST_K + slot] = (float)tlabels[src];
  }
}

extern "C" void kernel_launch(void* const* d_in, const int* in_sizes, int n_in,
                              void* d_out, int out_size, void* d_ws, size_t ws_size,
                              hipStream_t stream) {
  char* w = (char*)d_ws;
  auto carve = [&](size_t bytes) { char* p = w; w += (bytes + 255) & ~(size_t)255; return p; };
  int* labels   = (int*)carve((size_t)NB * P_TOT * 4);
  float* boxes  = (float*)carve((size_t)NB * P_TOT * 16);
  unsigned long long* keys = (unsigned long long*)carve((size_t)NB * P_TOT * 8);
  unsigned long long* colsupp = (unsigned long long*)carve((size_t)NB * PRE_K * 16 * 8);
  float* tboxes  = (float*)carve((size_t)NB * PRE_K * 16);
  float* tscores = (float*)carve((size_t)NB * PRE_K * 4);
  int* tlabels   = (int*)carve((size_t)NB * PRE_K * 4);

  const float* cls0 = (const float*)d_in[0];
  const float* reg0 = (const float*)d_in[1];
  const float* ctr0 = (const float*)d_in[2];
  const float* cls1 = (const float*)d_in[3];
  const float* reg1 = (const float*)d_in[4];
  const float* ctr1 = (const float*)d_in[5];
  const float* cls2 = (const float*)d_in[6];
  const float* reg2 = (const float*)d_in[7];
  const float* ctr2 = (const float*)d_in[8];
  const float* cls3 = (const float*)d_in[9];
  const float* reg3 = (const float*)d_in[10];
  const float* ctr3 = (const float*)d_in[11];
  const float* cls4 = (const float*)d_in[12];
  const float* reg4 = (const float*)d_in[13];
  const float* ctr4 = (const float*)d_in[14];

  dim3 dg((P4 + 31) / 32, NB);
  decode_kernel<<<dg, 256, 0, stream>>>(cls0, reg0, ctr0, cls1, reg1, ctr1,
                                        cls2, reg2, ctr2, cls3, reg3, ctr3,
                                        cls4, reg4, ctr4,
                                        labels, boxes, keys);
  topgather_kernel<<<NB, 1024, 0, stream>>>(keys, boxes, labels,
                                            tboxes, tscores, tlabels);
  dim3 gi(8, 16, NB);
  iou_kernel<<<gi, 128, 0, stream>>>(tboxes, tlabels, colsupp);
  greedyfin_kernel<<<NB, 1024, 0, stream>>>(colsupp, tscores, tboxes, tlabels, (float*)d_out);
}